// Round 1
// baseline (657.741 us; speedup 1.0000x reference)
//
#include <hip/hip_runtime.h>
#include <math.h>

#define B_ 4096
#define Q_ 1024
#define KD 256
#define N_ 16384
#define F_ 512

// ---------------------------------------------------------------------------
// k_qproj: qT[c][r] = sum_k ph[r][k]*Wq[k][c] + bq[c], stored TRANSPOSED
// [KD][B_] so the scores kernel can read q coalesced along rows.
// grid (KD/64, B_/64) = (4,64), block 256, 4x4 register tile.
// ---------------------------------------------------------------------------
__global__ __launch_bounds__(256)
void k_qproj(const float* __restrict__ ph, const float* __restrict__ Wq,
             const float* __restrict__ bq, float* __restrict__ qT) {
  __shared__ float As[16][64];  // [k][r]  (A^T)
  __shared__ float Ws[16][64];  // [k][c]
  const int tid = threadIdx.x;
  const int tx = tid & 15, ty = tid >> 4;
  const int c0 = blockIdx.x * 64, r0 = blockIdx.y * 64;
  float acc[4][4] = {};
  for (int kt = 0; kt < Q_; kt += 16) {
    {  // A tile: 64 rows x 16 k, coalesced 64B-per-row segments
      const int r = tid >> 2;
      const int k4 = (tid & 3) * 4;
      const float4 v = *reinterpret_cast<const float4*>(&ph[(r0 + r) * Q_ + kt + k4]);
      As[k4 + 0][r] = v.x; As[k4 + 1][r] = v.y;
      As[k4 + 2][r] = v.z; As[k4 + 3][r] = v.w;
    }
    {  // W tile: 16 k x 64 c
      const int kq = tid >> 4;
      const int c4 = (tid & 15) * 4;
      *reinterpret_cast<float4*>(&Ws[kq][c4]) =
          *reinterpret_cast<const float4*>(&Wq[(kt + kq) * KD + c0 + c4]);
    }
    __syncthreads();
#pragma unroll
    for (int k = 0; k < 16; ++k) {
      const float4 a = *reinterpret_cast<const float4*>(&As[k][ty * 4]);
      const float4 b = *reinterpret_cast<const float4*>(&Ws[k][tx * 4]);
      acc[0][0] = fmaf(a.x, b.x, acc[0][0]); acc[0][1] = fmaf(a.x, b.y, acc[0][1]);
      acc[0][2] = fmaf(a.x, b.z, acc[0][2]); acc[0][3] = fmaf(a.x, b.w, acc[0][3]);
      acc[1][0] = fmaf(a.y, b.x, acc[1][0]); acc[1][1] = fmaf(a.y, b.y, acc[1][1]);
      acc[1][2] = fmaf(a.y, b.z, acc[1][2]); acc[1][3] = fmaf(a.y, b.w, acc[1][3]);
      acc[2][0] = fmaf(a.z, b.x, acc[2][0]); acc[2][1] = fmaf(a.z, b.y, acc[2][1]);
      acc[2][2] = fmaf(a.z, b.z, acc[2][2]); acc[2][3] = fmaf(a.z, b.w, acc[2][3]);
      acc[3][0] = fmaf(a.w, b.x, acc[3][0]); acc[3][1] = fmaf(a.w, b.y, acc[3][1]);
      acc[3][2] = fmaf(a.w, b.z, acc[3][2]); acc[3][3] = fmaf(a.w, b.w, acc[3][3]);
    }
    __syncthreads();
  }
#pragma unroll
  for (int j = 0; j < 4; ++j) {
    const int c = c0 + tx * 4 + j;
    const float bj = bq[c];
    float4 v;
    v.x = acc[0][j] + bj; v.y = acc[1][j] + bj;
    v.z = acc[2][j] + bj; v.w = acc[3][j] + bj;
    *reinterpret_cast<float4*>(&qT[(size_t)c * B_ + r0 + ty * 4]) = v;  // 4 rows contiguous
  }
}

// ---------------------------------------------------------------------------
// k_transpose_keys: keysT[k][n] = keys[n][k].  One-time 33MB of traffic.
// grid (KD/64, N_/64) = (4,256), block 256.  tile padded to 69 to spread banks.
// ---------------------------------------------------------------------------
__global__ __launch_bounds__(256)
void k_transpose_keys(const float* __restrict__ keys, float* __restrict__ kTg) {
  __shared__ float tile[64][69];
  const int tid = threadIdx.x;
  const int k0 = blockIdx.x * 64, n0 = blockIdx.y * 64;
  {
    const int nl = tid >> 4;
    const int k4 = (tid & 15) * 4;
#pragma unroll
    for (int i = 0; i < 4; ++i) {
      const float4 v =
          *reinterpret_cast<const float4*>(&keys[(size_t)(n0 + nl + i * 16) * KD + k0 + k4]);
      tile[nl + i * 16][k4 + 0] = v.x; tile[nl + i * 16][k4 + 1] = v.y;
      tile[nl + i * 16][k4 + 2] = v.z; tile[nl + i * 16][k4 + 3] = v.w;
    }
  }
  __syncthreads();
  {
    const int kl = tid >> 4;
    const int n4 = (tid & 15) * 4;
#pragma unroll
    for (int i = 0; i < 4; ++i) {
      const int k = kl + i * 16;
      float4 v;
      v.x = tile[n4 + 0][k]; v.y = tile[n4 + 1][k];
      v.z = tile[n4 + 2][k]; v.w = tile[n4 + 3][k];
      *reinterpret_cast<float4*>(&kTg[(size_t)(k0 + k) * N_ + n0 + n4]) = v;
    }
  }
}

// ---------------------------------------------------------------------------
// k_scores_top2: block (bc,br) computes scores for rows [br*64,+64) x cols
// [bc*2048,+2048), K=256 inner, 4x4 register tile, outer-product LDS reads.
// Maintains per-thread running top-2 per row-slot, reduces to 2 candidates
// per (row, block) written to ws.  LDS: qT-resident 64KB + 16KB key tiles
// = 80KB -> 2 blocks/CU.  grid (8,64): consecutive blocks differ in bc ->
// each XCD sees one bc slice of keysT (2MB, L2-resident).
// ---------------------------------------------------------------------------
__global__ __launch_bounds__(256, 2)
void k_scores_top2(const float* __restrict__ qT, const float* __restrict__ kTg,
                   float* __restrict__ candV, int* __restrict__ candI) {
  __shared__ float qs[KD][64];  // [k][r]   64 KB
  __shared__ float ks[64][64];  // [k][c]   16 KB (aliased for candidate reduce)
  const int tid = threadIdx.x;
  const int tx = tid & 15, ty = tid >> 4;
  const int bc = blockIdx.x, br = blockIdx.y;
  const int row0 = br * 64;
  {  // stage all 256 k of q for our 64 rows (coalesced from qT)
    const int k = tid >> 4;
    const int r4 = (tid & 15) * 4;
#pragma unroll
    for (int i = 0; i < 16; ++i)
      *reinterpret_cast<float4*>(&qs[k + i * 16][r4]) =
          *reinterpret_cast<const float4*>(&qT[(size_t)(k + i * 16) * B_ + row0 + r4]);
  }
  float v1[4], v2[4]; int i1[4], i2[4];
#pragma unroll
  for (int i = 0; i < 4; ++i) { v1[i] = -INFINITY; v2[i] = -INFINITY; i1[i] = 0; i2[i] = 0; }

  for (int ct = 0; ct < 32; ++ct) {
    const int n0 = bc * 2048 + ct * 64;
    float acc[4][4] = {};
#pragma unroll 1
    for (int kc = 0; kc < 4; ++kc) {
      __syncthreads();
      {  // stage key tile [64k][64c]
        const int kk = tid >> 4;
        const int c4 = (tid & 15) * 4;
#pragma unroll
        for (int i = 0; i < 4; ++i)
          *reinterpret_cast<float4*>(&ks[kk + i * 16][c4]) =
              *reinterpret_cast<const float4*>(
                  &kTg[(size_t)(kc * 64 + kk + i * 16) * N_ + n0 + c4]);
      }
      __syncthreads();
#pragma unroll 16
      for (int kk = 0; kk < 64; ++kk) {
        const float4 a = *reinterpret_cast<const float4*>(&qs[kc * 64 + kk][ty * 4]);
        const float4 b = *reinterpret_cast<const float4*>(&ks[kk][tx * 4]);
        acc[0][0] = fmaf(a.x, b.x, acc[0][0]); acc[0][1] = fmaf(a.x, b.y, acc[0][1]);
        acc[0][2] = fmaf(a.x, b.z, acc[0][2]); acc[0][3] = fmaf(a.x, b.w, acc[0][3]);
        acc[1][0] = fmaf(a.y, b.x, acc[1][0]); acc[1][1] = fmaf(a.y, b.y, acc[1][1]);
        acc[1][2] = fmaf(a.y, b.z, acc[1][2]); acc[1][3] = fmaf(a.y, b.w, acc[1][3]);
        acc[2][0] = fmaf(a.z, b.x, acc[2][0]); acc[2][1] = fmaf(a.z, b.y, acc[2][1]);
        acc[2][2] = fmaf(a.z, b.z, acc[2][2]); acc[2][3] = fmaf(a.z, b.w, acc[2][3]);
        acc[3][0] = fmaf(a.w, b.x, acc[3][0]); acc[3][1] = fmaf(a.w, b.y, acc[3][1]);
        acc[3][2] = fmaf(a.w, b.z, acc[3][2]); acc[3][3] = fmaf(a.w, b.w, acc[3][3]);
      }
    }
    // fold this 4x4 tile into running top-2 (scores = acc / sqrt(256))
#pragma unroll
    for (int i = 0; i < 4; ++i) {
#pragma unroll
      for (int j = 0; j < 4; ++j) {
        const float v = acc[i][j] * 0.0625f;
        const int n = n0 + tx * 4 + j;
        if (v > v1[i]) { v2[i] = v1[i]; i2[i] = i1[i]; v1[i] = v; i1[i] = n; }
        else if (v > v2[i]) { v2[i] = v; i2[i] = n; }
      }
    }
  }
  __syncthreads();
  // cross-thread reduce: 16 tx-threads x 2 candidates per row -> top-2
  float* cv = &ks[0][0];            // 64*32 floats = 8KB
  int*   ci = (int*)&ks[32][0];     // 8KB
#pragma unroll
  for (int i = 0; i < 4; ++i) {
    const int r = ty * 4 + i;
    cv[r * 32 + tx * 2 + 0] = v1[i]; cv[r * 32 + tx * 2 + 1] = v2[i];
    ci[r * 32 + tx * 2 + 0] = i1[i]; ci[r * 32 + tx * 2 + 1] = i2[i];
  }
  __syncthreads();
  if (tid < 64) {
    const int r = tid;
    float b1 = -INFINITY, b2 = -INFINITY; int j1 = 0, j2 = 0;
    for (int s = 0; s < 32; ++s) {
      const int sl = (s + r) & 31;  // rotate start -> conflict-free banks
      const float v = cv[r * 32 + sl];
      const int idx = ci[r * 32 + sl];
      if (v > b1) { b2 = b1; j2 = j1; b1 = v; j1 = idx; }
      else if (v > b2) { b2 = v; j2 = idx; }
    }
    const int row = row0 + r;
    candV[row * 16 + bc * 2 + 0] = b1; candV[row * 16 + bc * 2 + 1] = b2;
    candI[row * 16 + bc * 2 + 0] = j1; candI[row * 16 + bc * 2 + 1] = j2;
  }
}

// ---------------------------------------------------------------------------
// k_finalize: per row, merge 16 candidates -> global top-2, 2-way softmax,
// scatter 2 alphas, gather+mix 2 emb rows, fused beta = sigmoid(ph.Wb+bb).
// grid 1024 x 256 threads (4 waves = 4 rows per block).
// ---------------------------------------------------------------------------
__global__ __launch_bounds__(256)
void k_finalize(const float* __restrict__ ph, const float* __restrict__ Wb,
                const float* __restrict__ bb, const float* __restrict__ embs,
                const float* __restrict__ candV, const int* __restrict__ candI,
                float* __restrict__ outEmb, float* __restrict__ outAlpha) {
  const int tid = threadIdx.x;
  const int lane = tid & 63;
  const int row = blockIdx.x * 4 + (tid >> 6);
  // beta = sigmoid(ph[row]·Wb + bb)
  float s = 0.f;
#pragma unroll
  for (int i = 0; i < 4; ++i) {
    const float4 a = *reinterpret_cast<const float4*>(&ph[(size_t)row * Q_ + lane * 4 + i * 256]);
    const float4 w = *reinterpret_cast<const float4*>(&Wb[lane * 4 + i * 256]);
    s += a.x * w.x + a.y * w.y + a.z * w.z + a.w * w.w;
  }
#pragma unroll
  for (int m = 32; m >= 1; m >>= 1) s += __shfl_xor(s, m);
  const float beta = 1.f / (1.f + expf(-(s + bb[0])));

  // top-2 of the 16 block-candidates (butterfly merge over lanes 0..15)
  float w1 = -INFINITY, w2 = -INFINITY; int j1 = 0, j2 = 0;
  if (lane < 16) { w1 = candV[row * 16 + lane]; j1 = candI[row * 16 + lane]; }
#pragma unroll
  for (int m = 1; m <= 8; m <<= 1) {
    const float o1 = __shfl_xor(w1, m); const int oj1 = __shfl_xor(j1, m);
    const float o2 = __shfl_xor(w2, m); const int oj2 = __shfl_xor(j2, m);
    if (o1 > w1) {
      const float nw2 = (w1 > o2) ? w1 : o2;
      const int  nj2 = (w1 > o2) ? j1 : oj2;
      w2 = nw2; j2 = nj2; w1 = o1; j1 = oj1;
    } else if (o1 > w2) { w2 = o1; j2 = oj1; }
  }
  w1 = __shfl(w1, 0); j1 = __shfl(j1, 0);
  w2 = __shfl(w2, 0); j2 = __shfl(j2, 0);

  const float t = expf(w2 - w1);           // <= 1
  const float inv = 1.f / (1.f + t);
  const float a1 = inv, a2 = t * inv;
  if (lane == 0) {
    outAlpha[(size_t)row * N_ + j1] = a1;
    outAlpha[(size_t)row * N_ + j2] = a2;
  }
#pragma unroll
  for (int i = 0; i < 2; ++i) {
    const int f = lane * 4 + i * 256;
    const float4 e1 = *reinterpret_cast<const float4*>(&embs[(size_t)j1 * F_ + f]);
    const float4 e2 = *reinterpret_cast<const float4*>(&embs[(size_t)j2 * F_ + f]);
    float4 o;
    o.x = beta * (a1 * e1.x + a2 * e2.x);
    o.y = beta * (a1 * e1.y + a2 * e2.y);
    o.z = beta * (a1 * e1.z + a2 * e2.z);
    o.w = beta * (a1 * e1.w + a2 * e2.w);
    *reinterpret_cast<float4*>(&outEmb[(size_t)row * F_ + f]) = o;
  }
}

// ---------------------------------------------------------------------------
extern "C" void kernel_launch(void* const* d_in, const int* in_sizes, int n_in,
                              void* d_out, int out_size, void* d_ws, size_t ws_size,
                              hipStream_t stream) {
  const float* ph   = (const float*)d_in[0];
  const float* keys = (const float*)d_in[1];
  const float* embs = (const float*)d_in[2];
  const float* Wq   = (const float*)d_in[3];
  const float* bq   = (const float*)d_in[4];
  const float* Wb   = (const float*)d_in[5];
  const float* bb   = (const float*)d_in[6];
  // d_in[7] = fallback (unused by reference), d_in[8] = topk (always 2 here)

  float* outEmb   = (float*)d_out;
  float* outAlpha = outEmb + (size_t)B_ * F_;

  // workspace layout (~20.5 MB)
  float* qT    = (float*)d_ws;                        // [KD][B_]   4 MB
  float* kTg   = qT + (size_t)KD * B_;                // [KD][N_]  16 MB
  float* candV = kTg + (size_t)KD * N_;               // [B_][16]  256 KB
  int*   candI = (int*)(candV + (size_t)B_ * 16);     // [B_][16]  256 KB

  // alpha is 2-sparse per row: zero the dense output, then scatter.
  hipMemsetAsync(outAlpha, 0, (size_t)B_ * N_ * sizeof(float), stream);

  k_qproj<<<dim3(KD / 64, B_ / 64), 256, 0, stream>>>(ph, Wq, bq, qT);
  k_transpose_keys<<<dim3(KD / 64, N_ / 64), 256, 0, stream>>>(keys, kTg);
  k_scores_top2<<<dim3(8, 64), 256, 0, stream>>>(qT, kTg, candV, candI);
  k_finalize<<<1024, 256, 0, stream>>>(ph, Wb, bb, embs, candV, candI, outEmb, outAlpha);
}

// Round 2
// 279.627 us; speedup vs baseline: 2.3522x; 2.3522x over previous
//
#include <hip/hip_runtime.h>
#include <math.h>

#define B_ 4096
#define Q_ 1024
#define KD 256
#define N_ 16384
#define F_ 512

typedef __attribute__((ext_vector_type(8))) short bhalf8;
typedef __attribute__((ext_vector_type(4))) float f32x4;

static __device__ __forceinline__ unsigned short f2bf(float f) {
  unsigned int u = __builtin_bit_cast(unsigned int, f);
  unsigned int r = (u + 0x7fffu + ((u >> 16) & 1u)) >> 16;
  return (unsigned short)r;
}

// ---------------------------------------------------------------------------
// k_qproj: q[r][c] = ph[r][:]·Wq[:][c] + bq[c]  (fp32, row-major) and a bf16
// copy qbf for the MFMA scoring kernel. grid (4,64), block 256, 4x4 tile.
// ---------------------------------------------------------------------------
__global__ __launch_bounds__(256)
void k_qproj(const float* __restrict__ ph, const float* __restrict__ Wq,
             const float* __restrict__ bq, float* __restrict__ q,
             unsigned short* __restrict__ qbf) {
  __shared__ float As[16][64];  // [k][r]
  __shared__ float Ws[16][64];  // [k][c]
  const int tid = threadIdx.x;
  const int tx = tid & 15, ty = tid >> 4;
  const int c0 = blockIdx.x * 64, r0 = blockIdx.y * 64;
  float acc[4][4] = {};
  for (int kt = 0; kt < Q_; kt += 16) {
    {
      const int r = tid >> 2;
      const int k4 = (tid & 3) * 4;
      const float4 v = *reinterpret_cast<const float4*>(&ph[(size_t)(r0 + r) * Q_ + kt + k4]);
      As[k4 + 0][r] = v.x; As[k4 + 1][r] = v.y;
      As[k4 + 2][r] = v.z; As[k4 + 3][r] = v.w;
    }
    {
      const int kq = tid >> 4;
      const int c4 = (tid & 15) * 4;
      *reinterpret_cast<float4*>(&Ws[kq][c4]) =
          *reinterpret_cast<const float4*>(&Wq[(size_t)(kt + kq) * KD + c0 + c4]);
    }
    __syncthreads();
#pragma unroll
    for (int k = 0; k < 16; ++k) {
      const float4 a = *reinterpret_cast<const float4*>(&As[k][ty * 4]);
      const float4 b = *reinterpret_cast<const float4*>(&Ws[k][tx * 4]);
      acc[0][0] = fmaf(a.x, b.x, acc[0][0]); acc[0][1] = fmaf(a.x, b.y, acc[0][1]);
      acc[0][2] = fmaf(a.x, b.z, acc[0][2]); acc[0][3] = fmaf(a.x, b.w, acc[0][3]);
      acc[1][0] = fmaf(a.y, b.x, acc[1][0]); acc[1][1] = fmaf(a.y, b.y, acc[1][1]);
      acc[1][2] = fmaf(a.y, b.z, acc[1][2]); acc[1][3] = fmaf(a.y, b.w, acc[1][3]);
      acc[2][0] = fmaf(a.z, b.x, acc[2][0]); acc[2][1] = fmaf(a.z, b.y, acc[2][1]);
      acc[2][2] = fmaf(a.z, b.z, acc[2][2]); acc[2][3] = fmaf(a.z, b.w, acc[2][3]);
      acc[3][0] = fmaf(a.w, b.x, acc[3][0]); acc[3][1] = fmaf(a.w, b.y, acc[3][1]);
      acc[3][2] = fmaf(a.w, b.z, acc[3][2]); acc[3][3] = fmaf(a.w, b.w, acc[3][3]);
    }
    __syncthreads();
  }
#pragma unroll
  for (int i = 0; i < 4; ++i) {
    const int r = r0 + ty * 4 + i;
    const int c = c0 + tx * 4;
    float4 v;
    v.x = acc[i][0] + bq[c + 0]; v.y = acc[i][1] + bq[c + 1];
    v.z = acc[i][2] + bq[c + 2]; v.w = acc[i][3] + bq[c + 3];
    *reinterpret_cast<float4*>(&q[(size_t)r * KD + c]) = v;
    ushort4 bv;
    bv.x = f2bf(v.x); bv.y = f2bf(v.y); bv.z = f2bf(v.z); bv.w = f2bf(v.w);
    *reinterpret_cast<ushort4*>(&qbf[(size_t)r * KD + c]) = bv;
  }
}

// ---------------------------------------------------------------------------
// k_convert_keys: keys fp32 -> bf16 (RNE), 8 elems/thread.
// ---------------------------------------------------------------------------
__global__ __launch_bounds__(256)
void k_convert_keys(const float* __restrict__ keys, unsigned short* __restrict__ kbf) {
  const size_t base = ((size_t)blockIdx.x * 256 + threadIdx.x) * 8;
  const float4 x = *reinterpret_cast<const float4*>(&keys[base]);
  const float4 y = *reinterpret_cast<const float4*>(&keys[base + 4]);
  bhalf8 o;
  o[0] = (short)f2bf(x.x); o[1] = (short)f2bf(x.y);
  o[2] = (short)f2bf(x.z); o[3] = (short)f2bf(x.w);
  o[4] = (short)f2bf(y.x); o[5] = (short)f2bf(y.y);
  o[6] = (short)f2bf(y.z); o[7] = (short)f2bf(y.w);
  *reinterpret_cast<bhalf8*>(&kbf[base]) = o;
}

// ---------------------------------------------------------------------------
// k_scores_mfma: approximate bf16 scores via MFMA + per-(lane,mtile) running
// top-4, reduced to per-block top-4 per row.
// Block (bc,br): rows [br*64,+64) x cols [bc*2048,+2048), K=256.
// 4 waves; wave w owns n-subtile [w*16,+16) of each staged 64-n key tile.
// q held ENTIRELY in registers (128 VGPR). Keys staged via global_load_lds
// (16B) into XOR-swizzled LDS (double-buffered 2x32KB).
// D = mfma(A=keys16x32, B=q32x16): D[n][m], n=(lane>>4)*4+reg, m=lane&15.
// ---------------------------------------------------------------------------
#define TOP4_INS(S1,S2,S3,S4,I1,I2,I3,I4, VAL, IDX)                          \
  if ((VAL) > (S2)) {                                                        \
    if ((VAL) > (S1)) { S4=S3;I4=I3; S3=S2;I3=I2; S2=S1;I2=I1; S1=(VAL);I1=(IDX); } \
    else              { S4=S3;I4=I3; S3=S2;I3=I2; S2=(VAL);I2=(IDX); }       \
  } else {                                                                   \
    if ((VAL) > (S3)) { S4=S3;I4=I3; S3=(VAL);I3=(IDX); }                    \
    else if ((VAL) > (S4)) { S4=(VAL);I4=(IDX); }                            \
  }

__global__ __launch_bounds__(256, 2)
void k_scores_mfma(const unsigned short* __restrict__ qbf,
                   const unsigned short* __restrict__ kbf,
                   float* __restrict__ candV, int* __restrict__ candI) {
  __shared__ __align__(16) char lds[65536];  // 2 x 32KB key tiles; reused for merge
  const int tid = threadIdx.x;
  const int wave = tid >> 6, lane = tid & 63;
  const int lm = lane & 15, lg = lane >> 4;
  const int bc = blockIdx.x, br = blockIdx.y;
  const int row0 = br * 64;

  // ---- q fragments in registers: qf[mt][kt] = q[row0+mt*16+lm][kt*32+lg*8 ..+8)
  bhalf8 qf[4][8];
#pragma unroll
  for (int mt = 0; mt < 4; ++mt)
#pragma unroll
    for (int kt = 0; kt < 8; ++kt)
      qf[mt][kt] = *reinterpret_cast<const bhalf8*>(
          &qbf[(size_t)(row0 + mt * 16 + lm) * KD + kt * 32 + lg * 8]);

  // ---- running top-4 per (lane, mt)
  float s1[4], s2[4], s3[4], s4[4];
  int   i1[4], i2[4], i3[4], i4[4];
#pragma unroll
  for (int mt = 0; mt < 4; ++mt) {
    s1[mt] = -INFINITY; s2[mt] = -INFINITY; s3[mt] = -INFINITY; s4[mt] = -INFINITY;
    i1[mt] = 0; i2[mt] = 0; i3[mt] = 0; i4[mt] = 0;
  }

  // staging: 32KB tile = 32 wave-instructions of 1KB; 8 per wave.
  // dest byte D = (wave*8+i)*1024 + lane*16 -> LDS row n=D>>9, col cb=D&511.
  // source col = cb ^ ((n&7)<<4)  (inverse of the read-side XOR swizzle).
  auto stage = [&](int bi, int t) {
    const int n0 = bc * 2048 + t * 64;
#pragma unroll
    for (int i = 0; i < 8; ++i) {
      const int D = (wave * 8 + i) * 1024 + lane * 16;
      const int n = D >> 9;
      const int cb = D & 511;
      const int csrc = cb ^ ((n & 7) << 4);
      const char* src = (const char*)kbf + ((size_t)(n0 + n) * 512 + csrc);
      __builtin_amdgcn_global_load_lds(
          (const __attribute__((address_space(1))) unsigned int*)src,
          (__attribute__((address_space(3))) unsigned int*)&lds[bi * 32768 + (wave * 8 + i) * 1024],
          16, 0, 0);
    }
  };

  stage(0, 0);
  __syncthreads();

  const int nrow = wave * 16 + lm;          // LDS row this lane reads
  const int swz = (nrow & 7) << 4;
  int bi = 0;
  for (int t = 0; t < 32; ++t) {
    if (t < 31) stage(bi ^ 1, t + 1);       // async prefetch, drains at barrier

    f32x4 acc0 = {0.f, 0.f, 0.f, 0.f}, acc1 = acc0, acc2 = acc0, acc3 = acc0;
    const char* kb = &lds[bi * 32768 + nrow * 512];
#pragma unroll
    for (int kt = 0; kt < 8; ++kt) {
      const bhalf8 af = *reinterpret_cast<const bhalf8*>(kb + ((kt * 64 + lg * 16) ^ swz));
      acc0 = __builtin_amdgcn_mfma_f32_16x16x32_bf16(af, qf[0][kt], acc0, 0, 0, 0);
      acc1 = __builtin_amdgcn_mfma_f32_16x16x32_bf16(af, qf[1][kt], acc1, 0, 0, 0);
      acc2 = __builtin_amdgcn_mfma_f32_16x16x32_bf16(af, qf[2][kt], acc2, 0, 0, 0);
      acc3 = __builtin_amdgcn_mfma_f32_16x16x32_bf16(af, qf[3][kt], acc3, 0, 0, 0);
    }
    // fold: lane holds n = nb + r (r=0..3) for m = row0 + mt*16 + lm
    const int nb = bc * 2048 + t * 64 + wave * 16 + lg * 4;
#pragma unroll
    for (int r = 0; r < 4; ++r) {
      const int nidx = nb + r;
      { const float v = acc0[r]; TOP4_INS(s1[0],s2[0],s3[0],s4[0],i1[0],i2[0],i3[0],i4[0], v, nidx) }
      { const float v = acc1[r]; TOP4_INS(s1[1],s2[1],s3[1],s4[1],i1[1],i2[1],i3[1],i4[1], v, nidx) }
      { const float v = acc2[r]; TOP4_INS(s1[2],s2[2],s3[2],s4[2],i1[2],i2[2],i3[2],i4[2], v, nidx) }
      { const float v = acc3[r]; TOP4_INS(s1[3],s2[3],s3[3],s4[3],i1[3],i2[3],i3[3],i4[3], v, nidx) }
    }
    __syncthreads();   // waits vmcnt(0): prefetch tile ready; buffers swap
    bi ^= 1;
  }

  // ---- block-level merge: 64 candidates per row -> top-4 per row.
  // Reuse LDS: cv[64][66] f32, ci[64][66] i32, mv/mi[64][17].
  float* cv = (float*)lds;                       // 16896 B
  int*   ci = (int*)(lds + 16896);               // 16896 B
  float* mv = (float*)(lds + 33792);             // 4352 B
  int*   mi = (int*)(lds + 38144);               // 4352 B
  {
    const int c = wave * 16 + lg * 4;
#pragma unroll
    for (int mt = 0; mt < 4; ++mt) {
      const int m = mt * 16 + lm;
      cv[m * 66 + c + 0] = s1[mt]; ci[m * 66 + c + 0] = i1[mt];
      cv[m * 66 + c + 1] = s2[mt]; ci[m * 66 + c + 1] = i2[mt];
      cv[m * 66 + c + 2] = s3[mt]; ci[m * 66 + c + 2] = i3[mt];
      cv[m * 66 + c + 3] = s4[mt]; ci[m * 66 + c + 3] = i4[mt];
    }
  }
  __syncthreads();
  {  // stage 1: 4 threads/row, each scans 16 -> top-4
    const int m = tid >> 2, part = tid & 3;
    float a1 = -INFINITY, a2 = -INFINITY, a3 = -INFINITY, a4 = -INFINITY;
    int b1 = 0, b2 = 0, b3 = 0, b4 = 0;
#pragma unroll
    for (int j = 0; j < 16; ++j) {
      const float v = cv[m * 66 + part * 16 + j];
      const int   x = ci[m * 66 + part * 16 + j];
      TOP4_INS(a1, a2, a3, a4, b1, b2, b3, b4, v, x)
    }
    mv[m * 17 + part * 4 + 0] = a1; mi[m * 17 + part * 4 + 0] = b1;
    mv[m * 17 + part * 4 + 1] = a2; mi[m * 17 + part * 4 + 1] = b2;
    mv[m * 17 + part * 4 + 2] = a3; mi[m * 17 + part * 4 + 2] = b3;
    mv[m * 17 + part * 4 + 3] = a4; mi[m * 17 + part * 4 + 3] = b4;
  }
  __syncthreads();
  if (tid < 64) {  // stage 2: merge 16 -> top-4, write global
    const int m = tid;
    float a1 = -INFINITY, a2 = -INFINITY, a3 = -INFINITY, a4 = -INFINITY;
    int b1 = 0, b2 = 0, b3 = 0, b4 = 0;
#pragma unroll
    for (int j = 0; j < 16; ++j) {
      const float v = mv[m * 17 + j];
      const int   x = mi[m * 17 + j];
      TOP4_INS(a1, a2, a3, a4, b1, b2, b3, b4, v, x)
    }
    const size_t o = (size_t)(row0 + m) * 32 + bc * 4;
    candV[o + 0] = a1; candI[o + 0] = b1;
    candV[o + 1] = a2; candI[o + 1] = b2;
    candV[o + 2] = a3; candI[o + 2] = b3;
    candV[o + 3] = a4; candI[o + 3] = b4;
  }
}

// ---------------------------------------------------------------------------
// k_finalize: one block per row. Zero alpha row, merge 32 approx candidates
// -> approx top-8, rescore those 8 in exact fp32, top-2 -> softmax -> scatter
// alpha + emb mix * sigmoid(ph·Wb+bb).
// ---------------------------------------------------------------------------
__global__ __launch_bounds__(256)
void k_finalize(const float* __restrict__ q, const float* __restrict__ keys,
                const float* __restrict__ ph, const float* __restrict__ Wb,
                const float* __restrict__ bb, const float* __restrict__ embs,
                const float* __restrict__ candV, const int* __restrict__ candI,
                float* __restrict__ outEmb, float* __restrict__ outAlpha) {
  __shared__ float red[4];
  __shared__ int   topIdx[8];
  __shared__ float resc[8];
  __shared__ float sParam[3];  // a1, a2, beta
  __shared__ int   sIdx[2];
  const int tid = threadIdx.x;
  const int wave = tid >> 6, lane = tid & 63;
  const int row = blockIdx.x;

  // Phase A: zero the alpha row (64KB), coalesced float4.
  float* arow = outAlpha + (size_t)row * N_;
  const float4 z4 = {0.f, 0.f, 0.f, 0.f};
#pragma unroll
  for (int i = 0; i < 16; ++i)
    *reinterpret_cast<float4*>(arow + (size_t)(i * 256 + tid) * 4) = z4;

  // Phase B: beta partial sums.
  {
    const float4 a = *reinterpret_cast<const float4*>(&ph[(size_t)row * Q_ + tid * 4]);
    const float4 w = *reinterpret_cast<const float4*>(&Wb[tid * 4]);
    float s = a.x * w.x + a.y * w.y + a.z * w.z + a.w * w.w;
#pragma unroll
    for (int m = 32; m >= 1; m >>= 1) s += __shfl_xor(s, m);
    if (lane == 0) red[wave] = s;
  }

  // Phase C (wave 0): approx top-8 of the 32 candidates by repeated wave-max.
  if (wave == 0) {
    float v = (lane < 32) ? candV[(size_t)row * 32 + lane] : -INFINITY;
    int   x = (lane < 32) ? candI[(size_t)row * 32 + lane] : -1;
#pragma unroll
    for (int it = 0; it < 8; ++it) {
      float mvx = v;
#pragma unroll
      for (int m = 32; m >= 1; m >>= 1) mvx = fmaxf(mvx, __shfl_xor(mvx, m));
      const unsigned long long bal = __ballot(v == mvx);
      const int src = __ffsll((long long)bal) - 1;
      if (lane == src) { topIdx[it] = x; v = -INFINITY; }
    }
  }
  __syncthreads();

  // Phase D: exact fp32 rescore of the 8 candidates; wave w does 2.
  {
#pragma unroll
    for (int h = 0; h < 2; ++h) {
      const int cnd = topIdx[wave * 2 + h];
      const float4 qv = *reinterpret_cast<const float4*>(&q[(size_t)row * KD + lane * 4]);
      const float4 kv = *reinterpret_cast<const float4*>(&keys[(size_t)cnd * KD + lane * 4]);
      float s = qv.x * kv.x + qv.y * kv.y + qv.z * kv.z + qv.w * kv.w;
#pragma unroll
      for (int m = 32; m >= 1; m >>= 1) s += __shfl_xor(s, m);
      if (lane == 0) resc[wave * 2 + h] = s * 0.0625f;
    }
  }
  __syncthreads();

  // Phase E (thread 0): top-2 of rescored (tie -> lower index), softmax, beta.
  if (tid == 0) {
    float w1 = -INFINITY, w2 = -INFINITY; int j1 = 0x7fffffff, j2 = 0x7fffffff;
#pragma unroll
    for (int c = 0; c < 8; ++c) {
      const float v = resc[c]; const int x = topIdx[c];
      const bool beat1 = (v > w1) || (v == w1 && x < j1);
      const bool beat2 = (v > w2) || (v == w2 && x < j2);
      if (beat1) { w2 = w1; j2 = j1; w1 = v; j1 = x; }
      else if (beat2) { w2 = v; j2 = x; }
    }
    const float t = expf(w2 - w1);
    const float inv = 1.f / (1.f + t);
    const float bsum = red[0] + red[1] + red[2] + red[3] + bb[0];
    sParam[0] = inv; sParam[1] = t * inv;
    sParam[2] = 1.f / (1.f + expf(-bsum));
    sIdx[0] = j1; sIdx[1] = j2;
  }
  __syncthreads();

  // Phase F: scatter alpha (after zeroing, ordered by the barriers above) and
  // emb mix.
  const float a1 = sParam[0], a2 = sParam[1], beta = sParam[2];
  const int j1 = sIdx[0], j2 = sIdx[1];
  if (tid == 0) { arow[j1] = a1; arow[j2] = a2; }
  if (tid < 128) {
    const int f = tid * 4;
    const float4 e1 = *reinterpret_cast<const float4*>(&embs[(size_t)j1 * F_ + f]);
    const float4 e2 = *reinterpret_cast<const float4*>(&embs[(size_t)j2 * F_ + f]);
    float4 o;
    o.x = beta * (a1 * e1.x + a2 * e2.x);
    o.y = beta * (a1 * e1.y + a2 * e2.y);
    o.z = beta * (a1 * e1.z + a2 * e2.z);
    o.w = beta * (a1 * e1.w + a2 * e2.w);
    *reinterpret_cast<float4*>(&outEmb[(size_t)row * F_ + f]) = o;
  }
}

// ---------------------------------------------------------------------------
extern "C" void kernel_launch(void* const* d_in, const int* in_sizes, int n_in,
                              void* d_out, int out_size, void* d_ws, size_t ws_size,
                              hipStream_t stream) {
  const float* ph   = (const float*)d_in[0];
  const float* keys = (const float*)d_in[1];
  const float* embs = (const float*)d_in[2];
  const float* Wq   = (const float*)d_in[3];
  const float* bq   = (const float*)d_in[4];
  const float* Wb   = (const float*)d_in[5];
  const float* bb   = (const float*)d_in[6];

  float* outEmb   = (float*)d_out;
  float* outAlpha = outEmb + (size_t)B_ * F_;

  // workspace (~15 MB)
  float*          q     = (float*)d_ws;                       // [B][KD] f32, 4MB
  unsigned short* qbf   = (unsigned short*)(q + (size_t)B_ * KD);   // 2MB
  unsigned short* kbf   = qbf + (size_t)B_ * KD;              // [N][KD] bf16, 8MB
  float*          candV = (float*)(kbf + (size_t)N_ * KD);    // [B][32] 512KB
  int*            candI = (int*)(candV + (size_t)B_ * 32);    // [B][32] 512KB

  k_qproj<<<dim3(KD / 64, B_ / 64), 256, 0, stream>>>(ph, Wq, bq, q, qbf);
  k_convert_keys<<<(N_ * KD / 8) / 256, 256, 0, stream>>>(keys, kbf);
  k_scores_mfma<<<dim3(8, 64), 256, 0, stream>>>(qbf, kbf, candV, candI);
  k_finalize<<<B_, 256, 0, stream>>>(q, keys, ph, Wb, bb, embs, candV, candI,
                                     outEmb, outAlpha);
}

// Round 3
// 176.611 us; speedup vs baseline: 3.7242x; 1.5833x over previous
//
#include <hip/hip_runtime.h>
#include <math.h>

#define B_ 4096
#define Q_ 1024
#define KD 256
#define N_ 16384
#define F_ 512

typedef __attribute__((ext_vector_type(8))) short bhalf8;
typedef __attribute__((ext_vector_type(4))) float f32x4;
typedef __attribute__((ext_vector_type(16))) float f32x16;

static __device__ __forceinline__ unsigned short f2bf(float f) {
  unsigned int u = __builtin_bit_cast(unsigned int, f);
  unsigned int r = (u + 0x7fffu + ((u >> 16) & 1u)) >> 16;
  return (unsigned short)r;
}
static __device__ __forceinline__ unsigned umaxu(unsigned a, unsigned b) { return a > b ? a : b; }
static __device__ __forceinline__ unsigned uminu(unsigned a, unsigned b) { return a < b ? a : b; }

// ---------------------------------------------------------------------------
// k_qproj: q[r][c] = ph[r][:]·Wq[:][c] + bq[c]  (fp32, row-major) and a bf16
// copy qbf for the MFMA scoring kernel. grid (4,64), block 256, 4x4 tile.
// ---------------------------------------------------------------------------
__global__ __launch_bounds__(256)
void k_qproj(const float* __restrict__ ph, const float* __restrict__ Wq,
             const float* __restrict__ bq, float* __restrict__ q,
             unsigned short* __restrict__ qbf) {
  __shared__ float As[16][64];  // [k][r]
  __shared__ float Ws[16][64];  // [k][c]
  const int tid = threadIdx.x;
  const int tx = tid & 15, ty = tid >> 4;
  const int c0 = blockIdx.x * 64, r0 = blockIdx.y * 64;
  float acc[4][4] = {};
  for (int kt = 0; kt < Q_; kt += 16) {
    {
      const int r = tid >> 2;
      const int k4 = (tid & 3) * 4;
      const float4 v = *reinterpret_cast<const float4*>(&ph[(size_t)(r0 + r) * Q_ + kt + k4]);
      As[k4 + 0][r] = v.x; As[k4 + 1][r] = v.y;
      As[k4 + 2][r] = v.z; As[k4 + 3][r] = v.w;
    }
    {
      const int kq = tid >> 4;
      const int c4 = (tid & 15) * 4;
      *reinterpret_cast<float4*>(&Ws[kq][c4]) =
          *reinterpret_cast<const float4*>(&Wq[(size_t)(kt + kq) * KD + c0 + c4]);
    }
    __syncthreads();
#pragma unroll
    for (int k = 0; k < 16; ++k) {
      const float4 a = *reinterpret_cast<const float4*>(&As[k][ty * 4]);
      const float4 b = *reinterpret_cast<const float4*>(&Ws[k][tx * 4]);
      acc[0][0] = fmaf(a.x, b.x, acc[0][0]); acc[0][1] = fmaf(a.x, b.y, acc[0][1]);
      acc[0][2] = fmaf(a.x, b.z, acc[0][2]); acc[0][3] = fmaf(a.x, b.w, acc[0][3]);
      acc[1][0] = fmaf(a.y, b.x, acc[1][0]); acc[1][1] = fmaf(a.y, b.y, acc[1][1]);
      acc[1][2] = fmaf(a.y, b.z, acc[1][2]); acc[1][3] = fmaf(a.y, b.w, acc[1][3]);
      acc[2][0] = fmaf(a.z, b.x, acc[2][0]); acc[2][1] = fmaf(a.z, b.y, acc[2][1]);
      acc[2][2] = fmaf(a.z, b.z, acc[2][2]); acc[2][3] = fmaf(a.z, b.w, acc[2][3]);
      acc[3][0] = fmaf(a.w, b.x, acc[3][0]); acc[3][1] = fmaf(a.w, b.y, acc[3][1]);
      acc[3][2] = fmaf(a.w, b.z, acc[3][2]); acc[3][3] = fmaf(a.w, b.w, acc[3][3]);
    }
    __syncthreads();
  }
#pragma unroll
  for (int i = 0; i < 4; ++i) {
    const int r = r0 + ty * 4 + i;
    const int c = c0 + tx * 4;
    float4 v;
    v.x = acc[i][0] + bq[c + 0]; v.y = acc[i][1] + bq[c + 1];
    v.z = acc[i][2] + bq[c + 2]; v.w = acc[i][3] + bq[c + 3];
    *reinterpret_cast<float4*>(&q[(size_t)r * KD + c]) = v;
    ushort4 bv;
    bv.x = f2bf(v.x); bv.y = f2bf(v.y); bv.z = f2bf(v.z); bv.w = f2bf(v.w);
    *reinterpret_cast<ushort4*>(&qbf[(size_t)r * KD + c]) = bv;
  }
}

// ---------------------------------------------------------------------------
// k_convert_keys: keys fp32 -> bf16 (RNE), 8 elems/thread.
// ---------------------------------------------------------------------------
__global__ __launch_bounds__(256)
void k_convert_keys(const float* __restrict__ keys, unsigned short* __restrict__ kbf) {
  const size_t base = ((size_t)blockIdx.x * 256 + threadIdx.x) * 8;
  const float4 x = *reinterpret_cast<const float4*>(&keys[base]);
  const float4 y = *reinterpret_cast<const float4*>(&keys[base + 4]);
  bhalf8 o;
  o[0] = (short)f2bf(x.x); o[1] = (short)f2bf(x.y);
  o[2] = (short)f2bf(x.z); o[3] = (short)f2bf(x.w);
  o[4] = (short)f2bf(y.x); o[5] = (short)f2bf(y.y);
  o[6] = (short)f2bf(y.z); o[7] = (short)f2bf(y.w);
  *reinterpret_cast<bhalf8*>(&kbf[base]) = o;
}

// ---------------------------------------------------------------------------
// k_scores_mfma (v2): 32x32x16 MFMA + branchless PACKED top-3 per lane.
// Block (bc,br): rows [br*64,+64) x cols [bc*1024,+1024).
// wave w = (rh=w>>1, ch=w&1): 32 rows x 32 cols sub-tile of each 64-col tile.
// Each lane owns ONE q-row (m = lane&31) and 16 key-cols per tile (per reg).
// K split into two 128-k halves -> 16KB staging tiles, 32KB LDS double-buf,
// 3 blocks/CU (launch_bounds cap). Packed candidate u32 =
//   (bits(score+512.f) & 0xFFFFF800) | col_in_block(11 bits)
// -> top-k kept with pure v_min_u32/v_max_u32, no branches, no index regs.
// Per row: 4 lane-slots x top-3 -> block top-4 -> candP[row][bc*4..+4).
// ---------------------------------------------------------------------------
__global__ __launch_bounds__(256, 3)
void k_scores_mfma(const unsigned short* __restrict__ qbf,
                   const unsigned short* __restrict__ kbf,
                   unsigned* __restrict__ candP) {
  __shared__ __align__(16) char lds[32768];   // 2 x 16KB key tiles (64c x 128k)
  __shared__ unsigned mbuf[64 * 12];
  const int tid = threadIdx.x;
  const int wave = tid >> 6, lane = tid & 63;
  const int l31 = lane & 31, lhi = lane >> 5;
  const int rh = wave >> 1, ch = wave & 1;
  const int bc = blockIdx.x, br = blockIdx.y;
  const int row0 = br * 64;
  const int m_row = row0 + rh * 32 + l31;

  // ---- q fragments (B-operand): qf[kt] = qbf[m_row][kt*16 + lhi*8 ..+8)
  bhalf8 qf[16];
#pragma unroll
  for (int kt = 0; kt < 16; ++kt)
    qf[kt] = *reinterpret_cast<const bhalf8*>(&qbf[(size_t)m_row * KD + kt * 16 + lhi * 8]);

  // staging: 16KB tile (64 cols x 128 k, col-major rows of 256B). LDS dest is
  // linear (wave-uniform + lane*16); source address pre-applies the read-side
  // XOR swizzle ((col&15)<<4) so swizzled reads see the right bytes.
  auto stage = [&](int bi, int u) {
    const int t = u >> 1, kh = u & 1;
#pragma unroll
    for (int i = 0; i < 4; ++i) {
      const int D = i * 4096 + tid * 16;
      const int colt = D >> 8;                 // 0..63
      const int kb = D & 255;
      const int kbs = kb ^ ((colt & 15) << 4);
      const char* src = (const char*)kbf +
          ((size_t)(bc * 1024 + t * 64 + colt) * 512 + kh * 256 + kbs);
      __builtin_amdgcn_global_load_lds(
          (const __attribute__((address_space(1))) unsigned int*)src,
          (__attribute__((address_space(3))) unsigned int*)(lds + bi * 16384 + D),
          16, 0, 0);
    }
  };

  unsigned P1 = 0u, P2 = 0u, P3 = 0u;   // packed top-3, descending
  const int acol = ch * 32 + l31;       // col within 64-col tile (A-operand row)
  const int swz = (acol & 15) << 4;
  const int kofs = lhi * 16;            // A k-offset bytes (8 bf16)

  stage(0, 0);
  __syncthreads();

  int buf = 0;
  for (int t = 0; t < 16; ++t) {
    f32x16 acc = {};
#pragma unroll
    for (int kh = 0; kh < 2; ++kh) {
      const int u = t * 2 + kh;
      if (u < 31) stage(buf ^ 1, u + 1);
      const char* kb = lds + buf * 16384 + acol * 256;
#pragma unroll
      for (int kt = 0; kt < 8; ++kt) {
        const bhalf8 af = *reinterpret_cast<const bhalf8*>(kb + ((kt * 32 + kofs) ^ swz));
        acc = __builtin_amdgcn_mfma_f32_32x32x16_bf16(af, qf[kh * 8 + kt], acc, 0, 0, 0);
      }
      if (kh == 1) {
        // fold 16 cols of this row into packed top-3 (branchless)
        const int cb = t * 64 + ch * 32 + lhi * 4;
#pragma unroll
        for (int r = 0; r < 16; ++r) {
          const int rofs = (r & 3) + 8 * (r >> 2);
          const unsigned p =
              (__builtin_bit_cast(unsigned, acc[r] + 512.f) & 0xFFFFF800u) |
              (unsigned)(cb + rofs);
          const unsigned w1 = uminu(P1, p); P1 = umaxu(P1, p);
          const unsigned w2 = uminu(P2, w1); P2 = umaxu(P2, w1);
          P3 = umaxu(P3, w2);
        }
      }
      __syncthreads();   // prefetch tile ready (vmcnt drain) + safe to overwrite
      buf ^= 1;
    }
  }

  // ---- block merge: per row 4 slots x 3 -> top-4 -> global candP
  {
    const int mrow = rh * 32 + l31;
    const int slot = ch * 2 + lhi;
    mbuf[mrow * 12 + slot * 3 + 0] = P1;
    mbuf[mrow * 12 + slot * 3 + 1] = P2;
    mbuf[mrow * 12 + slot * 3 + 2] = P3;
  }
  __syncthreads();
  if (tid < 64) {
    unsigned T1 = 0u, T2 = 0u, T3 = 0u, T4 = 0u;
#pragma unroll
    for (int j = 0; j < 12; ++j) {
      const unsigned p = mbuf[tid * 12 + j];
      const unsigned w1 = uminu(T1, p); T1 = umaxu(T1, p);
      const unsigned w2 = uminu(T2, w1); T2 = umaxu(T2, w1);
      const unsigned w3 = uminu(T3, w2); T3 = umaxu(T3, w2);
      T4 = umaxu(T4, w3);
    }
    const size_t o = (size_t)(row0 + tid) * 64 + bc * 4;
    candP[o + 0] = T1; candP[o + 1] = T2; candP[o + 2] = T3; candP[o + 3] = T4;
  }
}

// ---------------------------------------------------------------------------
// k_finalize: one block per row. Zero alpha row, take top-8 of the 64 packed
// candidates (u32 compare = approx-score order), rescore those 8 in exact
// fp32, top-2 -> softmax -> scatter alpha + emb mix * sigmoid(ph·Wb+bb).
// ---------------------------------------------------------------------------
__global__ __launch_bounds__(256)
void k_finalize(const float* __restrict__ q, const float* __restrict__ keys,
                const float* __restrict__ ph, const float* __restrict__ Wb,
                const float* __restrict__ bb, const float* __restrict__ embs,
                const unsigned* __restrict__ candP,
                float* __restrict__ outEmb, float* __restrict__ outAlpha) {
  __shared__ float red[4];
  __shared__ int   topIdx[8];
  __shared__ float resc[8];
  __shared__ float sParam[3];  // a1, a2, beta
  __shared__ int   sIdx[2];
  const int tid = threadIdx.x;
  const int wave = tid >> 6, lane = tid & 63;
  const int row = blockIdx.x;

  // Phase A: zero the alpha row (64KB), coalesced float4.
  float* arow = outAlpha + (size_t)row * N_;
  const float4 z4 = {0.f, 0.f, 0.f, 0.f};
#pragma unroll
  for (int i = 0; i < 16; ++i)
    *reinterpret_cast<float4*>(arow + (size_t)(i * 256 + tid) * 4) = z4;

  // Phase B: beta partial sums.
  {
    const float4 a = *reinterpret_cast<const float4*>(&ph[(size_t)row * Q_ + tid * 4]);
    const float4 w = *reinterpret_cast<const float4*>(&Wb[tid * 4]);
    float s = a.x * w.x + a.y * w.y + a.z * w.z + a.w * w.w;
#pragma unroll
    for (int m = 32; m >= 1; m >>= 1) s += __shfl_xor(s, m);
    if (lane == 0) red[wave] = s;
  }

  // Phase C (wave 0): top-8 of 64 packed candidates by repeated wave-max.
  if (wave == 0) {
    unsigned p = candP[(size_t)row * 64 + lane];
    const int mycol = (lane >> 2) * 1024 + (int)(p & 0x7FFu);
#pragma unroll
    for (int it = 0; it < 8; ++it) {
      unsigned mx = p;
#pragma unroll
      for (int m = 32; m >= 1; m >>= 1) {
        const unsigned o = (unsigned)__shfl_xor((int)mx, m);
        mx = mx > o ? mx : o;
      }
      const unsigned long long bal = __ballot(p == mx);
      const int src = __ffsll((unsigned long long)bal) - 1;
      if (lane == src) { topIdx[it] = mycol; p = 0u; }
    }
  }
  __syncthreads();

  // Phase D: exact fp32 rescore of the 8 candidates; wave w does 2.
  {
#pragma unroll
    for (int h = 0; h < 2; ++h) {
      const int cnd = topIdx[wave * 2 + h];
      const float4 qv = *reinterpret_cast<const float4*>(&q[(size_t)row * KD + lane * 4]);
      const float4 kv = *reinterpret_cast<const float4*>(&keys[(size_t)cnd * KD + lane * 4]);
      float s = qv.x * kv.x + qv.y * kv.y + qv.z * kv.z + qv.w * kv.w;
#pragma unroll
      for (int m = 32; m >= 1; m >>= 1) s += __shfl_xor(s, m);
      if (lane == 0) resc[wave * 2 + h] = s * 0.0625f;
    }
  }
  __syncthreads();

  // Phase E (thread 0): top-2 of rescored (tie -> lower index), softmax, beta.
  if (tid == 0) {
    float w1 = -INFINITY, w2 = -INFINITY; int j1 = 0x7fffffff, j2 = 0x7fffffff;
#pragma unroll
    for (int c = 0; c < 8; ++c) {
      const float v = resc[c]; const int x = topIdx[c];
      const bool beat1 = (v > w1) || (v == w1 && x < j1);
      const bool beat2 = (v > w2) || (v == w2 && x < j2);
      if (beat1) { w2 = w1; j2 = j1; w1 = v; j1 = x; }
      else if (beat2) { w2 = v; j2 = x; }
    }
    const float t = expf(w2 - w1);
    const float inv = 1.f / (1.f + t);
    const float bsum = red[0] + red[1] + red[2] + red[3] + bb[0];
    sParam[0] = inv; sParam[1] = t * inv;
    sParam[2] = 1.f / (1.f + expf(-bsum));
    sIdx[0] = j1; sIdx[1] = j2;
  }
  __syncthreads();

  // Phase F: scatter alpha and emb mix.
  const float a1 = sParam[0], a2 = sParam[1], beta = sParam[2];
  const int j1 = sIdx[0], j2 = sIdx[1];
  if (tid == 0) { arow[j1] = a1; arow[j2] = a2; }
  if (tid < 128) {
    const int f = tid * 4;
    const float4 e1 = *reinterpret_cast<const float4*>(&embs[(size_t)j1 * F_ + f]);
    const float4 e2 = *reinterpret_cast<const float4*>(&embs[(size_t)j2 * F_ + f]);
    float4 o;
    o.x = beta * (a1 * e1.x + a2 * e2.x);
    o.y = beta * (a1 * e1.y + a2 * e2.y);
    o.z = beta * (a1 * e1.z + a2 * e2.z);
    o.w = beta * (a1 * e1.w + a2 * e2.w);
    *reinterpret_cast<float4*>(&outEmb[(size_t)row * F_ + f]) = o;
  }
}

// ---------------------------------------------------------------------------
extern "C" void kernel_launch(void* const* d_in, const int* in_sizes, int n_in,
                              void* d_out, int out_size, void* d_ws, size_t ws_size,
                              hipStream_t stream) {
  const float* ph   = (const float*)d_in[0];
  const float* keys = (const float*)d_in[1];
  const float* embs = (const float*)d_in[2];
  const float* Wq   = (const float*)d_in[3];
  const float* bq   = (const float*)d_in[4];
  const float* Wb   = (const float*)d_in[5];
  const float* bb   = (const float*)d_in[6];

  float* outEmb   = (float*)d_out;
  float* outAlpha = outEmb + (size_t)B_ * F_;

  // workspace (~15 MB)
  float*          q     = (float*)d_ws;                             // 4MB
  unsigned short* qbf   = (unsigned short*)(q + (size_t)B_ * KD);   // 2MB
  unsigned short* kbf   = qbf + (size_t)B_ * KD;                    // 8MB
  unsigned*       candP = (unsigned*)(kbf + (size_t)N_ * KD);       // 1MB

  k_qproj<<<dim3(KD / 64, B_ / 64), 256, 0, stream>>>(ph, Wq, bq, q, qbf);
  k_convert_keys<<<(N_ * KD / 8) / 256, 256, 0, stream>>>(keys, kbf);
  k_scores_mfma<<<dim3(16, 64), 256, 0, stream>>>(qbf, kbf, candP);
  k_finalize<<<B_, 256, 0, stream>>>(q, keys, ph, Wb, bb, embs, candP,
                                     outEmb, outAlpha);
}